// Round 1
// baseline (366.070 us; speedup 1.0000x reference)
//
#include <hip/hip_runtime.h>
#include <cstdint>
#include <math.h>

// GeometricAttention: B=4,H=8,N=2048, D = 8*16 (mv, IPF signs on q) + 16 (s) = 144
// Flash attention, bf16 MFMA 16x16x32, fp32 accumulate, online softmax (exp2 domain).

#define B_    4
#define H_    8
#define BH    32
#define N_    2048
#define DMV   128
#define DS    16
#define D_    144
#define BM    128          // Q rows per block
#define BN    64           // KV rows per iteration
#define NKIT  (N_ / BN)    // 32
#define KSTR  168          // sK row stride (bf16 elems) — padded vs 160 for bank spread
#define VSTR  72           // sVT row stride
#define PSTR  72           // sP row stride

// scale * log2(e): softmax computed with exp2
#define QSCALE 0.12022458674074693f  // (1/12) * 1.4426950408889634

typedef __bf16 bf16_8 __attribute__((ext_vector_type(8)));
typedef __bf16 bf16_4 __attribute__((ext_vector_type(4)));
typedef __bf16 bf16_2 __attribute__((ext_vector_type(2)));
typedef float  f32x4  __attribute__((ext_vector_type(4)));
typedef float  f32x2  __attribute__((ext_vector_type(2)));

__device__ __forceinline__ f32x4 mfma16(bf16_8 a, bf16_8 b, f32x4 c) {
  return __builtin_amdgcn_mfma_f32_16x16x32_bf16(a, b, c, 0, 0, 0);
}

// Load one Q A-fragment (8 bf16 along k) for global row pointers; applies IPF sign
// (on mv part only) and QSCALE. k0 = ks*32 + quad*8, multiple of 8.
__device__ __forceinline__ bf16_8 load_q_frag(const float* qmv_row, const float* qs_row, int k0) {
  bf16_8 f;
  if (k0 < DMV) {
    const f32x4* p = (const f32x4*)(qmv_row + k0);
    f32x4 a = p[0], b = p[1];
    // IPF = [1,1,-1,-1,-1,-1,-1,-1, 1,1,1,1,1,1,-1,-1]; k0&8 selects which half.
    int hi = k0 & 8;
#pragma unroll
    for (int j = 0; j < 8; ++j) {
      float v = (j < 4) ? a[j] : b[j - 4];
      bool pos = hi ? (j < 6) : (j < 2);
      f[j] = (__bf16)(v * (pos ? QSCALE : -QSCALE));
    }
  } else if (k0 < D_) {
    const f32x4* p = (const f32x4*)(qs_row + (k0 - DMV));
    f32x4 a = p[0], b = p[1];
#pragma unroll
    for (int j = 0; j < 8; ++j) {
      float v = (j < 4) ? a[j] : b[j - 4];
      f[j] = (__bf16)(v * QSCALE);
    }
  } else {
#pragma unroll
    for (int j = 0; j < 8; ++j) f[j] = (__bf16)0.0f;
  }
  return f;
}

__global__ __launch_bounds__(256, 2)
void geo_attn_kernel(const float* __restrict__ q_mv, const float* __restrict__ k_mv,
                     const float* __restrict__ v_mv, const float* __restrict__ q_s,
                     const float* __restrict__ k_s,  const float* __restrict__ v_s,
                     float* __restrict__ out)
{
  __shared__ __bf16 sK[BN * KSTR];       // 21504 B  K tile, row-major [n][k]
  __shared__ __bf16 sVT[D_ * VSTR];      // 20736 B  V tile transposed [d][n]
  __shared__ __bf16 sP[4 * 32 * PSTR];   // 18432 B  per-wave P (C-layout -> A-layout)

  const int tid  = threadIdx.x;
  const int w    = tid >> 6;        // wave 0..3
  const int lane = tid & 63;
  const int l15  = lane & 15;
  const int quad = lane >> 4;
  const int bh    = blockIdx.y;
  const int qbase = blockIdx.x * BM;
  const size_t bh_n = (size_t)bh * N_;

  // ---- zero sK pad columns [144,168) once (never overwritten later)
  for (int idx = tid; idx < BN * (KSTR - D_); idx += 256) {
    int r = idx / (KSTR - D_), cc = idx - r * (KSTR - D_);
    sK[r * KSTR + D_ + cc] = (__bf16)0.0f;
  }

  // ---- Q fragments in registers for whole kernel: qf[rowgroup][ks]
  bf16_8 qf[2][5];
#pragma unroll
  for (int rg = 0; rg < 2; ++rg) {
    int mrow = qbase + 32 * w + 16 * rg + l15;
    const float* qmv_row = q_mv + (bh_n + mrow) * DMV;
    const float* qs_row  = q_s  + (bh_n + mrow) * DS;
#pragma unroll
    for (int ks = 0; ks < 5; ++ks)
      qf[rg][ks] = load_q_frag(qmv_row, qs_row, ks * 32 + quad * 8);
  }

  // ---- accumulators + softmax state (replicated across the 16 lanes of each quad)
  f32x4 of[2][9];
#pragma unroll
  for (int rg = 0; rg < 2; ++rg)
#pragma unroll
    for (int n9 = 0; n9 < 9; ++n9)
#pragma unroll
      for (int r = 0; r < 4; ++r) of[rg][n9][r] = 0.0f;
  float m_i[2][4], l_i[2][4];
#pragma unroll
  for (int rg = 0; rg < 2; ++rg)
#pragma unroll
    for (int r = 0; r < 4; ++r) { m_i[rg][r] = -INFINITY; l_i[rg][r] = 0.0f; }

  // staging thread maps
  const int krow = tid >> 2, kc = tid & 3;   // K: 64 rows x 4 chunks(36 cols)
  const int vp = tid & 31, vdc = tid >> 5;   // V: 32 row-pairs x 8 chunks(18 cols)

  for (int it = 0; it < NKIT; ++it) {
    const int kb = it * BN;

    // ======== stage K tile (fp32 -> bf16, row-major, stride KSTR) ========
    {
      const float* mvrow = k_mv + (bh_n + kb + krow) * DMV;
      const float* srow  = k_s  + (bh_n + kb + krow) * DS;
      __bf16* dst = &sK[krow * KSTR];
      if (kc < 3) {
#pragma unroll
        for (int i = 0; i < 9; ++i) {
          f32x4 x = *(const f32x4*)(mvrow + kc * 36 + 4 * i);
          bf16_4 wv; wv[0]=(__bf16)x[0]; wv[1]=(__bf16)x[1]; wv[2]=(__bf16)x[2]; wv[3]=(__bf16)x[3];
          *(bf16_4*)&dst[kc * 36 + 4 * i] = wv;
        }
      } else {
#pragma unroll
        for (int i = 0; i < 5; ++i) {
          f32x4 x = *(const f32x4*)(mvrow + 108 + 4 * i);
          bf16_4 wv; wv[0]=(__bf16)x[0]; wv[1]=(__bf16)x[1]; wv[2]=(__bf16)x[2]; wv[3]=(__bf16)x[3];
          *(bf16_4*)&dst[108 + 4 * i] = wv;
        }
#pragma unroll
        for (int i = 0; i < 4; ++i) {
          f32x4 x = *(const f32x4*)(srow + 4 * i);
          bf16_4 wv; wv[0]=(__bf16)x[0]; wv[1]=(__bf16)x[1]; wv[2]=(__bf16)x[2]; wv[3]=(__bf16)x[3];
          *(bf16_4*)&dst[128 + 4 * i] = wv;
        }
      }
    }

    // ======== stage V tile TRANSPOSED: sVT[d][n], packed pair-of-rows writes ========
    {
      const float* r0mv = v_mv + (bh_n + kb + 2 * vp) * DMV;
      const float* r1mv = r0mv + DMV;
      const float* r0s  = v_s  + (bh_n + kb + 2 * vp) * DS;
      const float* r1s  = r0s + DS;
      if (vdc < 7) {
#pragma unroll
        for (int i = 0; i < 9; ++i) {
          int d = vdc * 18 + 2 * i;
          f32x2 x0 = *(const f32x2*)(r0mv + d);
          f32x2 x1 = *(const f32x2*)(r1mv + d);
          bf16_2 p0; p0[0] = (__bf16)x0[0]; p0[1] = (__bf16)x1[0];
          bf16_2 p1; p1[0] = (__bf16)x0[1]; p1[1] = (__bf16)x1[1];
          *(bf16_2*)&sVT[(d    ) * VSTR + 2 * vp] = p0;
          *(bf16_2*)&sVT[(d + 1) * VSTR + 2 * vp] = p1;
        }
      } else {
        { // d = 126,127 from mv
          f32x2 x0 = *(const f32x2*)(r0mv + 126);
          f32x2 x1 = *(const f32x2*)(r1mv + 126);
          bf16_2 p0; p0[0] = (__bf16)x0[0]; p0[1] = (__bf16)x1[0];
          bf16_2 p1; p1[0] = (__bf16)x0[1]; p1[1] = (__bf16)x1[1];
          *(bf16_2*)&sVT[126 * VSTR + 2 * vp] = p0;
          *(bf16_2*)&sVT[127 * VSTR + 2 * vp] = p1;
        }
#pragma unroll
        for (int i = 0; i < 8; ++i) { // d = 128..143 from s
          f32x2 x0 = *(const f32x2*)(r0s + 2 * i);
          f32x2 x1 = *(const f32x2*)(r1s + 2 * i);
          bf16_2 p0; p0[0] = (__bf16)x0[0]; p0[1] = (__bf16)x1[0];
          bf16_2 p1; p1[0] = (__bf16)x0[1]; p1[1] = (__bf16)x1[1];
          *(bf16_2*)&sVT[(128 + 2 * i    ) * VSTR + 2 * vp] = p0;
          *(bf16_2*)&sVT[(128 + 2 * i + 1) * VSTR + 2 * vp] = p1;
        }
      }
    }
    __syncthreads();

    // ======== S = Q K^T  (per wave: 32 rows x 64 cols) ========
    f32x4 sf[2][4];
#pragma unroll
    for (int rg = 0; rg < 2; ++rg)
#pragma unroll
      for (int nt = 0; nt < 4; ++nt)
#pragma unroll
        for (int r = 0; r < 4; ++r) sf[rg][nt][r] = 0.0f;

#pragma unroll
    for (int ks = 0; ks < 5; ++ks) {
      bf16_8 kbf[4];
#pragma unroll
      for (int nt = 0; nt < 4; ++nt)
        kbf[nt] = *(const bf16_8*)&sK[(nt * 16 + l15) * KSTR + ks * 32 + quad * 8];
#pragma unroll
      for (int rg = 0; rg < 2; ++rg)
#pragma unroll
        for (int nt = 0; nt < 4; ++nt)
          sf[rg][nt] = mfma16(qf[rg][ks], kbf[nt], sf[rg][nt]);
    }

    // ======== online softmax (exp2 domain) + write P to per-wave LDS ========
#pragma unroll
    for (int rg = 0; rg < 2; ++rg) {
      float al[4];
#pragma unroll
      for (int r = 0; r < 4; ++r) {
        float mx = fmaxf(fmaxf(sf[rg][0][r], sf[rg][1][r]), fmaxf(sf[rg][2][r], sf[rg][3][r]));
#pragma unroll
        for (int off = 1; off < 16; off <<= 1) mx = fmaxf(mx, __shfl_xor(mx, off));
        float mnew = fmaxf(m_i[rg][r], mx);
        al[r] = __builtin_amdgcn_exp2f(m_i[rg][r] - mnew);
        m_i[rg][r] = mnew;
        float rs = 0.0f;
#pragma unroll
        for (int nt = 0; nt < 4; ++nt) {
          float p = __builtin_amdgcn_exp2f(sf[rg][nt][r] - mnew);
          sf[rg][nt][r] = p;
          rs += p;
        }
#pragma unroll
        for (int off = 1; off < 16; off <<= 1) rs += __shfl_xor(rs, off);
        l_i[rg][r] = l_i[rg][r] * al[r] + rs;
      }
      // rescale O accumulator (C-layout: component r <-> row quad*4+r)
#pragma unroll
      for (int n9 = 0; n9 < 9; ++n9)
#pragma unroll
        for (int r = 0; r < 4; ++r) of[rg][n9][r] *= al[r];
      // P: C-layout -> LDS (row = 16*rg + quad*4 + r, col = nt*16 + l15)
#pragma unroll
      for (int nt = 0; nt < 4; ++nt)
#pragma unroll
        for (int r = 0; r < 4; ++r)
          sP[w * (32 * PSTR) + (16 * rg + quad * 4 + r) * PSTR + nt * 16 + l15] =
              (__bf16)sf[rg][nt][r];
    }
    // P region is wave-private: drain LDS queue, no block barrier needed
    asm volatile("s_waitcnt lgkmcnt(0)" ::: "memory");

    // ======== O += P V ========
#pragma unroll
    for (int ks = 0; ks < 2; ++ks) {
      bf16_8 pa[2];
#pragma unroll
      for (int rg = 0; rg < 2; ++rg)
        pa[rg] = *(const bf16_8*)&sP[w * (32 * PSTR) + (16 * rg + l15) * PSTR + ks * 32 + quad * 8];
#pragma unroll
      for (int n9 = 0; n9 < 9; ++n9) {
        bf16_8 vb = *(const bf16_8*)&sVT[(n9 * 16 + l15) * VSTR + ks * 32 + quad * 8];
#pragma unroll
        for (int rg = 0; rg < 2; ++rg)
          of[rg][n9] = mfma16(pa[rg], vb, of[rg][n9]);
      }
    }
    __syncthreads();  // protect sK/sVT before next iteration's staging
  }

  // ======== epilogue: O /= l, write out_mv then out_s (fp32) ========
  float* out_mv = out;
  float* out_s  = out + (size_t)BH * N_ * DMV;
#pragma unroll
  for (int rg = 0; rg < 2; ++rg) {
    float inv[4];
#pragma unroll
    for (int r = 0; r < 4; ++r) inv[r] = __builtin_amdgcn_rcpf(l_i[rg][r]);
#pragma unroll
    for (int n9 = 0; n9 < 9; ++n9) {
      int d = n9 * 16 + l15;
#pragma unroll
      for (int r = 0; r < 4; ++r) {
        int row = qbase + 32 * w + 16 * rg + quad * 4 + r;
        float val = of[rg][n9][r] * inv[r];
        if (n9 < 8) out_mv[(bh_n + row) * DMV + d] = val;
        else        out_s [(bh_n + row) * DS + l15] = val;
      }
    }
  }
}

extern "C" void kernel_launch(void* const* d_in, const int* in_sizes, int n_in,
                              void* d_out, int out_size, void* d_ws, size_t ws_size,
                              hipStream_t stream) {
  (void)in_sizes; (void)n_in; (void)out_size; (void)d_ws; (void)ws_size;
  const float* q_mv = (const float*)d_in[0];
  const float* k_mv = (const float*)d_in[1];
  const float* v_mv = (const float*)d_in[2];
  const float* q_s  = (const float*)d_in[3];
  const float* k_s  = (const float*)d_in[4];
  const float* v_s  = (const float*)d_in[5];
  float* out = (float*)d_out;
  dim3 grid(N_ / BM, BH);
  geo_attn_kernel<<<grid, 256, 0, stream>>>(q_mv, k_mv, v_mv, q_s, k_s, v_s, out);
}

// Round 2
// 318.892 us; speedup vs baseline: 1.1479x; 1.1479x over previous
//
#include <hip/hip_runtime.h>
#include <cstdint>
#include <math.h>

// GeometricAttention: B=4,H=8,N=2048, D = 8*16 (mv, IPF signs on q) + 16 (s) = 144
// R2: pre-pass packs K->bf16 [bh][n][168] and V^T->bf16 tile-blocked [bh][32][144][72]
// into d_ws; main flash kernel stages tiles via global_load_lds_dwordx4 (no per-iter
// convert VALU). bf16 MFMA 16x16x32, fp32 accumulate, online softmax in exp2 domain.

#define B_    4
#define H_    8
#define BH    32
#define N_    2048
#define DMV   128
#define DS    16
#define D_    144
#define BM    128          // Q rows per block
#define BN    64           // KV rows per iteration
#define NKIT  (N_ / BN)    // 32
#define KSTR  168          // packed K row stride (bf16) — bank offset 20 mod 32 (2-way, free)
#define VSTR  72           // packed V^T row stride (bf16) — bank offset 4 mod 32 (2-way, free)
#define PSTR  72           // sP row stride
#define KTILE_B   (BN * KSTR * 2)        // 21504 = 21*1024
#define VTILE_B   (D_ * VSTR * 2)        // 20736 = 20*1024 + 256
#define KP_BYTES  ((size_t)BH * N_ * KSTR * 2)          // 22,020,096
#define VT_BYTES  ((size_t)BH * NKIT * D_ * VSTR * 2)   // 21,233,664

// scale * log2(e): softmax computed with exp2
#define QSCALE 0.12022458674074693f  // (1/12) * 1.4426950408889634

typedef __bf16 bf16_8 __attribute__((ext_vector_type(8)));
typedef __bf16 bf16_4 __attribute__((ext_vector_type(4)));
typedef __bf16 bf16_2 __attribute__((ext_vector_type(2)));
typedef float  f32x4  __attribute__((ext_vector_type(4)));

#define GLOAD_LDS16(g, l)                                                     \
  __builtin_amdgcn_global_load_lds(                                           \
      (const __attribute__((address_space(1))) void*)(g),                     \
      (__attribute__((address_space(3))) void*)(l), 16, 0, 0)

__device__ __forceinline__ f32x4 mfma16(bf16_8 a, bf16_8 b, f32x4 c) {
  return __builtin_amdgcn_mfma_f32_16x16x32_bf16(a, b, c, 0, 0, 0);
}

__device__ __forceinline__ bf16_4 cvt4(f32x4 x) {
  bf16_4 w; w[0]=(__bf16)x[0]; w[1]=(__bf16)x[1]; w[2]=(__bf16)x[2]; w[3]=(__bf16)x[3];
  return w;
}

// ---------------- pre-pass 1: K -> bf16 packed [bh*n][168], pad cols zeroed ----------
__global__ __launch_bounds__(256)
void pack_k(const float* __restrict__ kmv, const float* __restrict__ ks_,
            __bf16* __restrict__ kp) {
  const int row  = blockIdx.x * 4 + (threadIdx.x >> 6);  // one wave per row
  const int lane = threadIdx.x & 63;
  const float* mv = kmv + (size_t)row * DMV;
  const float* s  = ks_ + (size_t)row * DS;
  __bf16* dst = kp + (size_t)row * KSTR;
  if (lane < 32) {
    *(bf16_4*)&dst[lane * 4] = cvt4(*(const f32x4*)(mv + lane * 4));
  } else if (lane < 36) {
    *(bf16_4*)&dst[128 + (lane - 32) * 4] = cvt4(*(const f32x4*)(s + (lane - 32) * 4));
  } else if (lane < 42) {
    bf16_4 z; z[0]=(__bf16)0.f; z[1]=(__bf16)0.f; z[2]=(__bf16)0.f; z[3]=(__bf16)0.f;
    *(bf16_4*)&dst[144 + (lane - 36) * 4] = z;   // pad cols 144..167
  }
}

// ---------------- pre-pass 2: V^T -> bf16 tile-blocked [bh*32 tiles][144][72] --------
__global__ __launch_bounds__(256)
void pack_vt(const float* __restrict__ vmv, const float* __restrict__ vs,
             __bf16* __restrict__ vt) {
  __shared__ __bf16 sT[64 * 148];
  const int tile = blockIdx.x;            // bh*32 + nb; row base = tile*64 (2048=32*64)
  const int t = threadIdx.x;
  const int n = t >> 2, c = t & 3;
  const float* mv = vmv + (size_t)(tile * 64 + n) * DMV;
  const float* s  = vs  + (size_t)(tile * 64 + n) * DS;
  __bf16* row = &sT[n * 148];
  if (c < 3) {
#pragma unroll
    for (int i = 0; i < 9; ++i)
      *(bf16_4*)&row[c * 36 + 4 * i] = cvt4(*(const f32x4*)(mv + c * 36 + 4 * i));
  } else {
#pragma unroll
    for (int i = 0; i < 5; ++i)
      *(bf16_4*)&row[108 + 4 * i] = cvt4(*(const f32x4*)(mv + 108 + 4 * i));
#pragma unroll
    for (int i = 0; i < 4; ++i)
      *(bf16_4*)&row[128 + 4 * i] = cvt4(*(const f32x4*)(s + 4 * i));
  }
  __syncthreads();
  __bf16* vtt = vt + (size_t)tile * (D_ * VSTR);
  for (int idx = t; idx < D_ * 32; idx += 256) {
    int d = idx >> 5, j = idx & 31;
    bf16_2 p; p[0] = sT[(2 * j) * 148 + d]; p[1] = sT[(2 * j + 1) * 148 + d];
    *(bf16_2*)&vtt[d * VSTR + 2 * j] = p;     // coalesced 4B writes along j
  }
}

// ---------------- Q fragment load: IPF sign + scale, fp32 -> bf16 --------------------
__device__ __forceinline__ bf16_8 load_q_frag(const float* qmv_row, const float* qs_row, int k0) {
  bf16_8 f;
  if (k0 < DMV) {
    const f32x4* p = (const f32x4*)(qmv_row + k0);
    f32x4 a = p[0], b = p[1];
    // IPF = [1,1,-1,-1,-1,-1,-1,-1, 1,1,1,1,1,1,-1,-1]; k0&8 selects which half.
    int hi = k0 & 8;
#pragma unroll
    for (int j = 0; j < 8; ++j) {
      float v = (j < 4) ? a[j] : b[j - 4];
      bool pos = hi ? (j < 6) : (j < 2);
      f[j] = (__bf16)(v * (pos ? QSCALE : -QSCALE));
    }
  } else if (k0 < D_) {
    const f32x4* p = (const f32x4*)(qs_row + (k0 - DMV));
    f32x4 a = p[0], b = p[1];
#pragma unroll
    for (int j = 0; j < 8; ++j) {
      float v = (j < 4) ? a[j] : b[j - 4];
      f[j] = (__bf16)(v * QSCALE);
    }
  } else {
#pragma unroll
    for (int j = 0; j < 8; ++j) f[j] = (__bf16)0.0f;
  }
  return f;
}

// ---------------- main flash kernel --------------------------------------------------
__global__ __launch_bounds__(256, 2)
void geo_attn_kernel(const float* __restrict__ q_mv, const float* __restrict__ q_s,
                     const __bf16* __restrict__ kp, const __bf16* __restrict__ vt,
                     float* __restrict__ out)
{
  __shared__ __bf16 sK[BN * KSTR];       // 21504 B  K tile, row-major [n][k]
  __shared__ __bf16 sVT[D_ * VSTR];      // 20736 B  V tile transposed [d][n]
  __shared__ __bf16 sP[4 * 32 * PSTR];   // 18432 B  per-wave P (C-layout -> A-layout)

  const int tid  = threadIdx.x;
  const int w    = tid >> 6;        // wave 0..3
  const int lane = tid & 63;
  const int l15  = lane & 15;
  const int quad = lane >> 4;
  const int bh    = blockIdx.y;
  const int qbase = blockIdx.x * BM;
  const size_t bh_n = (size_t)bh * N_;

  // ---- Q fragments in registers for whole kernel: qf[rowgroup][ks]
  bf16_8 qf[2][5];
#pragma unroll
  for (int rg = 0; rg < 2; ++rg) {
    int mrow = qbase + 32 * w + 16 * rg + l15;
    const float* qmv_row = q_mv + (bh_n + mrow) * DMV;
    const float* qs_row  = q_s  + (bh_n + mrow) * DS;
#pragma unroll
    for (int ks = 0; ks < 5; ++ks)
      qf[rg][ks] = load_q_frag(qmv_row, qs_row, ks * 32 + quad * 8);
  }

  // ---- accumulators + softmax state (replicated across the 16 lanes of each quad)
  f32x4 of[2][9];
#pragma unroll
  for (int rg = 0; rg < 2; ++rg)
#pragma unroll
    for (int n9 = 0; n9 < 9; ++n9)
#pragma unroll
      for (int r = 0; r < 4; ++r) of[rg][n9][r] = 0.0f;
  float m_i[2][4], l_i[2][4];
#pragma unroll
  for (int rg = 0; rg < 2; ++rg)
#pragma unroll
    for (int r = 0; r < 4; ++r) { m_i[rg][r] = -INFINITY; l_i[rg][r] = 0.0f; }

  const __bf16* kbase = kp + bh_n * KSTR;

  for (int it = 0; it < NKIT; ++it) {
    // ======== stage K,V tiles via direct global->LDS DMA (dwordx4) ========
    {
      const __bf16* kt = kbase + (size_t)(it * BN) * KSTR;         // 21*1024 B
      const __bf16* vtt = vt + (size_t)(bh * NKIT + it) * (D_ * VSTR); // 20*1024+256 B
#pragma unroll
      for (int i = w; i < 21; i += 4)
        GLOAD_LDS16(kt + i * 512 + lane * 8, &sK[i * 512 + lane * 8]);
#pragma unroll
      for (int i = w; i < 20; i += 4)
        GLOAD_LDS16(vtt + i * 512 + lane * 8, &sVT[i * 512 + lane * 8]);
      if (w == 0 && lane < 16)   // tail 256 B of V tile
        GLOAD_LDS16(vtt + 20 * 512 + lane * 8, &sVT[20 * 512 + lane * 8]);
    }
    __syncthreads();   // drains vmcnt -> tiles resident

    // ======== S = Q K^T  (per wave: 32 rows x 64 cols) ========
    f32x4 sf[2][4];
#pragma unroll
    for (int rg = 0; rg < 2; ++rg)
#pragma unroll
      for (int nt = 0; nt < 4; ++nt)
#pragma unroll
        for (int r = 0; r < 4; ++r) sf[rg][nt][r] = 0.0f;

#pragma unroll
    for (int ks = 0; ks < 5; ++ks) {
      bf16_8 kbf[4];
#pragma unroll
      for (int nt = 0; nt < 4; ++nt)
        kbf[nt] = *(const bf16_8*)&sK[(nt * 16 + l15) * KSTR + ks * 32 + quad * 8];
#pragma unroll
      for (int rg = 0; rg < 2; ++rg)
#pragma unroll
        for (int nt = 0; nt < 4; ++nt)
          sf[rg][nt] = mfma16(qf[rg][ks], kbf[nt], sf[rg][nt]);
    }

    // ======== online softmax (exp2 domain) + write P to per-wave LDS ========
#pragma unroll
    for (int rg = 0; rg < 2; ++rg) {
      float al[4];
#pragma unroll
      for (int r = 0; r < 4; ++r) {
        float mx = fmaxf(fmaxf(sf[rg][0][r], sf[rg][1][r]), fmaxf(sf[rg][2][r], sf[rg][3][r]));
#pragma unroll
        for (int off = 1; off < 16; off <<= 1) mx = fmaxf(mx, __shfl_xor(mx, off));
        float mnew = fmaxf(m_i[rg][r], mx);
        al[r] = __builtin_amdgcn_exp2f(m_i[rg][r] - mnew);
        m_i[rg][r] = mnew;
        float rs = 0.0f;
#pragma unroll
        for (int nt = 0; nt < 4; ++nt) {
          float p = __builtin_amdgcn_exp2f(sf[rg][nt][r] - mnew);
          sf[rg][nt][r] = p;
          rs += p;
        }
#pragma unroll
        for (int off = 1; off < 16; off <<= 1) rs += __shfl_xor(rs, off);
        l_i[rg][r] = l_i[rg][r] * al[r] + rs;
      }
      // rescale O accumulator (C-layout: component r <-> row quad*4+r)
#pragma unroll
      for (int n9 = 0; n9 < 9; ++n9)
#pragma unroll
        for (int r = 0; r < 4; ++r) of[rg][n9][r] *= al[r];
      // P: C-layout -> LDS (row = 16*rg + quad*4 + r, col = nt*16 + l15)
#pragma unroll
      for (int nt = 0; nt < 4; ++nt)
#pragma unroll
        for (int r = 0; r < 4; ++r)
          sP[w * (32 * PSTR) + (16 * rg + quad * 4 + r) * PSTR + nt * 16 + l15] =
              (__bf16)sf[rg][nt][r];
    }
    // P region is wave-private: drain LDS queue, no block barrier needed
    asm volatile("s_waitcnt lgkmcnt(0)" ::: "memory");

    // ======== O += P V ========
#pragma unroll
    for (int ks = 0; ks < 2; ++ks) {
      bf16_8 pa[2];
#pragma unroll
      for (int rg = 0; rg < 2; ++rg)
        pa[rg] = *(const bf16_8*)&sP[w * (32 * PSTR) + (16 * rg + l15) * PSTR + ks * 32 + quad * 8];
#pragma unroll
      for (int n9 = 0; n9 < 9; ++n9) {
        bf16_8 vb = *(const bf16_8*)&sVT[(n9 * 16 + l15) * VSTR + ks * 32 + quad * 8];
#pragma unroll
        for (int rg = 0; rg < 2; ++rg)
          of[rg][n9] = mfma16(pa[rg], vb, of[rg][n9]);
      }
    }
    __syncthreads();  // protect sK/sVT before next iteration's staging
  }

  // ======== epilogue: O /= l, write out_mv then out_s (fp32) ========
  float* out_mv = out;
  float* out_s  = out + (size_t)BH * N_ * DMV;
#pragma unroll
  for (int rg = 0; rg < 2; ++rg) {
    float inv[4];
#pragma unroll
    for (int r = 0; r < 4; ++r) inv[r] = __builtin_amdgcn_rcpf(l_i[rg][r]);
#pragma unroll
    for (int n9 = 0; n9 < 9; ++n9) {
      int d = n9 * 16 + l15;
#pragma unroll
      for (int r = 0; r < 4; ++r) {
        int row = qbase + 32 * w + 16 * rg + quad * 4 + r;
        float val = of[rg][n9][r] * inv[r];
        if (n9 < 8) out_mv[(bh_n + row) * DMV + d] = val;
        else        out_s [(bh_n + row) * DS + l15] = val;
      }
    }
  }
}

extern "C" void kernel_launch(void* const* d_in, const int* in_sizes, int n_in,
                              void* d_out, int out_size, void* d_ws, size_t ws_size,
                              hipStream_t stream) {
  (void)in_sizes; (void)n_in; (void)out_size; (void)ws_size;
  const float* q_mv = (const float*)d_in[0];
  const float* k_mv = (const float*)d_in[1];
  const float* v_mv = (const float*)d_in[2];
  const float* q_s  = (const float*)d_in[3];
  const float* k_s  = (const float*)d_in[4];
  const float* v_s  = (const float*)d_in[5];
  float* out = (float*)d_out;

  __bf16* kp = (__bf16*)d_ws;                              // 22,020,096 B
  __bf16* vt = (__bf16*)((char*)d_ws + KP_BYTES);          // 21,233,664 B

  pack_k<<<BH * N_ / 4, 256, 0, stream>>>(k_mv, k_s, kp);
  pack_vt<<<BH * NKIT, 256, 0, stream>>>(v_mv, v_s, vt);

  dim3 grid(N_ / BM, BH);
  geo_attn_kernel<<<grid, 256, 0, stream>>>(q_mv, q_s, kp, vt, out);
}

// Round 3
// 273.577 us; speedup vs baseline: 1.3381x; 1.1656x over previous
//
#include <hip/hip_runtime.h>
#include <cstdint>
#include <math.h>

// GeometricAttention: B=4,H=8,N=2048, D = 8*16 (mv, IPF signs on q) + 16 (s) = 144
// R3: S^T orientation (softmax row on l15 -> 2-shuffle reductions, b64 P-writes),
// sP aliased into sK (LDS 42.2KB -> 512-thr blocks, 16 waves/CU), efficient prepasses.

#define BH    32
#define N_    2048
#define DMV   128
#define DS    16
#define D_    144
#define BM    128          // Q rows per block (8 waves x 16 rows)
#define BN    64           // KV rows per iteration
#define NKIT  (N_ / BN)    // 32
#define KSTR  168          // packed K row stride (bf16); tile = 21*1024 B
#define VSTR  72           // packed V^T row stride (bf16); tile = 20*1024+256 B
#define PSTR  72           // sP row stride (aliased into sK)
#define KP_BYTES  ((size_t)BH * N_ * KSTR * 2)          // 22,020,096
#define QSCALE 0.12022458674074693f  // (1/12) * log2(e)

typedef __bf16 bf16_8 __attribute__((ext_vector_type(8)));
typedef __bf16 bf16_4 __attribute__((ext_vector_type(4)));
typedef __bf16 bf16_2 __attribute__((ext_vector_type(2)));
typedef float  f32x4  __attribute__((ext_vector_type(4)));

#define GLOAD_LDS16(g, l)                                                     \
  __builtin_amdgcn_global_load_lds(                                           \
      (const __attribute__((address_space(1))) void*)(g),                     \
      (__attribute__((address_space(3))) void*)(l), 16, 0, 0)

__device__ __forceinline__ f32x4 mfma16(bf16_8 a, bf16_8 b, f32x4 c) {
  return __builtin_amdgcn_mfma_f32_16x16x32_bf16(a, b, c, 0, 0, 0);
}

__device__ __forceinline__ bf16_4 cvt4(f32x4 x) {
  bf16_4 w; w[0]=(__bf16)x[0]; w[1]=(__bf16)x[1]; w[2]=(__bf16)x[2]; w[3]=(__bf16)x[3];
  return w;
}

// ---------------- pre-pass 1: K -> bf16 packed [bh*n][168], coalesced chunks --------
// one thread = one 16B output chunk (8 bf16); 21 chunks/row (last 3 = zero pad)
__global__ __launch_bounds__(256)
void pack_k(const float* __restrict__ kmv, const float* __restrict__ ks_,
            __bf16* __restrict__ kp) {
  const unsigned g = blockIdx.x * 256 + threadIdx.x;   // < 65536*21
  const unsigned row = g / 21u, seg = g - row * 21u;
  bf16_8 o;
  if (seg < 16) {
    const f32x4* p = (const f32x4*)(kmv + (size_t)row * DMV + seg * 8);
    f32x4 a = p[0], b = p[1];
#pragma unroll
    for (int j = 0; j < 8; ++j) o[j] = (__bf16)((j < 4) ? a[j] : b[j - 4]);
  } else if (seg < 18) {
    const f32x4* p = (const f32x4*)(ks_ + (size_t)row * DS + (seg - 16) * 8);
    f32x4 a = p[0], b = p[1];
#pragma unroll
    for (int j = 0; j < 8; ++j) o[j] = (__bf16)((j < 4) ? a[j] : b[j - 4]);
  } else {
#pragma unroll
    for (int j = 0; j < 8; ++j) o[j] = (__bf16)0.0f;
  }
  *(bf16_8*)(kp + (size_t)row * KSTR + seg * 8) = o;
}

// ---------------- pre-pass 2: V^T -> bf16 tile-blocked [bh*32 tiles][144][72] --------
#define TSTR 156   // sT stride: write banks 2-way free, read 4-way (acceptable)
__global__ __launch_bounds__(256)
void pack_vt(const float* __restrict__ vmv, const float* __restrict__ vs,
             __bf16* __restrict__ vt) {
  __shared__ __bf16 sT[64 * TSTR];
  const int tile = blockIdx.x;            // bh*32 + nb
  const int t = threadIdx.x;
  const int n = t >> 2, c = t & 3;
  const float* mv = vmv + (size_t)(tile * 64 + n) * DMV;
  const float* s  = vs  + (size_t)(tile * 64 + n) * DS;
  __bf16* row = &sT[n * TSTR];
  if (c < 3) {
#pragma unroll
    for (int i = 0; i < 9; ++i)
      *(bf16_4*)&row[c * 36 + 4 * i] = cvt4(*(const f32x4*)(mv + c * 36 + 4 * i));
  } else {
#pragma unroll
    for (int i = 0; i < 5; ++i)
      *(bf16_4*)&row[108 + 4 * i] = cvt4(*(const f32x4*)(mv + 108 + 4 * i));
#pragma unroll
    for (int i = 0; i < 4; ++i)
      *(bf16_4*)&row[128 + 4 * i] = cvt4(*(const f32x4*)(s + 4 * i));
  }
  __syncthreads();
  __bf16* vtt = vt + (size_t)tile * (D_ * VSTR);
#pragma unroll
  for (int k = 0; k < 18; ++k) {
    int idx = t + 256 * k;                // d major, j minor
    int d = idx >> 5, j = idx & 31;
    bf16_2 p; p[0] = sT[(2 * j) * TSTR + d]; p[1] = sT[(2 * j + 1) * TSTR + d];
    *(bf16_2*)&vtt[d * VSTR + 2 * j] = p; // 128B contiguous per 32 lanes
  }
}

// ---------------- Q fragment load: IPF sign + scale, fp32 -> bf16 --------------------
__device__ __forceinline__ bf16_8 load_q_frag(const float* qmv_row, const float* qs_row, int k0) {
  bf16_8 f;
  if (k0 < DMV) {
    const f32x4* p = (const f32x4*)(qmv_row + k0);
    f32x4 a = p[0], b = p[1];
    // IPF = [1,1,-1,-1,-1,-1,-1,-1, 1,1,1,1,1,1,-1,-1]; k0&8 selects which half.
    int hi = k0 & 8;
#pragma unroll
    for (int j = 0; j < 8; ++j) {
      float v = (j < 4) ? a[j] : b[j - 4];
      bool pos = hi ? (j < 6) : (j < 2);
      f[j] = (__bf16)(v * (pos ? QSCALE : -QSCALE));
    }
  } else if (k0 < D_) {
    const f32x4* p = (const f32x4*)(qs_row + (k0 - DMV));
    f32x4 a = p[0], b = p[1];
#pragma unroll
    for (int j = 0; j < 8; ++j) {
      float v = (j < 4) ? a[j] : b[j - 4];
      f[j] = (__bf16)(v * QSCALE);
    }
  } else {
#pragma unroll
    for (int j = 0; j < 8; ++j) f[j] = (__bf16)0.0f;
  }
  return f;
}

// ---------------- main flash kernel (512 threads, 8 waves x 16 Q-rows) ---------------
__global__ __launch_bounds__(512, 4)
void geo_attn_kernel(const float* __restrict__ q_mv, const float* __restrict__ q_s,
                     const __bf16* __restrict__ kp, const __bf16* __restrict__ vt,
                     float* __restrict__ out)
{
  __shared__ __bf16 sK[BN * KSTR];       // 21504 B; after QK phase aliased as sP
  __shared__ __bf16 sVT[D_ * VSTR];      // 20736 B

  const int tid  = threadIdx.x;
  const int w    = tid >> 6;        // wave 0..7
  const int lane = tid & 63;
  const int l15  = lane & 15;
  const int quad = lane >> 4;
  const int bh    = blockIdx.y;
  const int qbase = blockIdx.x * BM;
  const size_t bh_n = (size_t)bh * N_;

  __bf16* sP = sK + w * (16 * PSTR);     // per-wave 16x72 region inside sK

  // ---- Q fragments in registers: B-operand layout, lane l15 = Q row m
  bf16_8 qf[5];
  {
    int mrow = qbase + 16 * w + l15;
    const float* qmv_row = q_mv + (bh_n + mrow) * DMV;
    const float* qs_row  = q_s  + (bh_n + mrow) * DS;
#pragma unroll
    for (int ks = 0; ks < 5; ++ks)
      qf[ks] = load_q_frag(qmv_row, qs_row, ks * 32 + quad * 8);
  }

  f32x4 of[9];
#pragma unroll
  for (int n9 = 0; n9 < 9; ++n9)
#pragma unroll
    for (int r = 0; r < 4; ++r) of[n9][r] = 0.0f;
  float m_i = -INFINITY, l_i = 0.0f;     // per Q-row m = l15, replicated over quads

  const __bf16* kbase = kp + bh_n * KSTR;

  for (int it = 0; it < NKIT; ++it) {
    // ======== stage K,V tiles via global->LDS DMA ========
    {
      const __bf16* kt  = kbase + (size_t)(it * BN) * KSTR;
      const __bf16* vtt = vt + (size_t)(bh * NKIT + it) * (D_ * VSTR);
      for (int i = w; i < 21; i += 8)
        GLOAD_LDS16(kt + i * 512 + lane * 8, &sK[i * 512 + lane * 8]);
      for (int i = w; i < 20; i += 8)
        GLOAD_LDS16(vtt + i * 512 + lane * 8, &sVT[i * 512 + lane * 8]);
      if (w == 0 && lane < 16)
        GLOAD_LDS16(vtt + 20 * 512 + lane * 8, &sVT[20 * 512 + lane * 8]);
    }
    __syncthreads();   // vmcnt drained -> tiles resident

    // ======== S^T = K Q^T : sf[nt] holds rows n=nt*16+quad*4+r, cols m=l15 ========
    f32x4 sf[4];
#pragma unroll
    for (int nt = 0; nt < 4; ++nt)
#pragma unroll
      for (int r = 0; r < 4; ++r) sf[nt][r] = 0.0f;
#pragma unroll
    for (int ks = 0; ks < 5; ++ks) {
#pragma unroll
      for (int nt = 0; nt < 4; ++nt) {
        bf16_8 kb = *(const bf16_8*)&sK[(nt * 16 + l15) * KSTR + ks * 32 + quad * 8];
        sf[nt] = mfma16(kb, qf[ks], sf[nt]);
      }
    }
    __syncthreads();   // all sK reads done before sP (alias) writes

    // ======== online softmax: row m = l15, reduce across quads (2 shuffles) ========
    {
      float mx = sf[0][0];
#pragma unroll
      for (int nt = 0; nt < 4; ++nt)
#pragma unroll
        for (int r = 0; r < 4; ++r) mx = fmaxf(mx, sf[nt][r]);
      mx = fmaxf(mx, __shfl_xor(mx, 16));
      mx = fmaxf(mx, __shfl_xor(mx, 32));
      float mnew = fmaxf(m_i, mx);
      float al = __builtin_amdgcn_exp2f(m_i - mnew);
      m_i = mnew;
      float rs = 0.0f;
#pragma unroll
      for (int nt = 0; nt < 4; ++nt)
#pragma unroll
        for (int r = 0; r < 4; ++r) {
          float p = __builtin_amdgcn_exp2f(sf[nt][r] - mnew);
          sf[nt][r] = p;
          rs += p;
        }
      rs += __shfl_xor(rs, 16);
      rs += __shfl_xor(rs, 32);
      l_i = l_i * al + rs;

      // P write: row m=l15, col n=nt*16+quad*4+r -> one b64 per nt
#pragma unroll
      for (int nt = 0; nt < 4; ++nt) {
        bf16_4 pw;
#pragma unroll
        for (int r = 0; r < 4; ++r) pw[r] = (__bf16)sf[nt][r];
        *(bf16_4*)&sP[l15 * PSTR + nt * 16 + quad * 4] = pw;
      }
      asm volatile("s_waitcnt lgkmcnt(0)" ::: "memory");  // sP is wave-private

      // alpha to O-row indexing (m' = quad*4+r): srclane = 16*quad + 4*quad + r
      float alr[4];
#pragma unroll
      for (int r = 0; r < 4; ++r) alr[r] = __shfl(al, 20 * quad + r);
#pragma unroll
      for (int n9 = 0; n9 < 9; ++n9)
#pragma unroll
        for (int r = 0; r < 4; ++r) of[n9][r] *= alr[r];
    }

    // ======== O += P V ========
#pragma unroll
    for (int ks = 0; ks < 2; ++ks) {
      bf16_8 pa = *(const bf16_8*)&sP[l15 * PSTR + ks * 32 + quad * 8];
#pragma unroll
      for (int n9 = 0; n9 < 9; ++n9) {
        bf16_8 vb = *(const bf16_8*)&sVT[(n9 * 16 + l15) * VSTR + ks * 32 + quad * 8];
        of[n9] = mfma16(pa, vb, of[n9]);
      }
    }
    __syncthreads();  // sVT/sP reads done before next iteration's staging
  }

  // ======== epilogue: O /= l (redistributed to O-rows), write fp32 ========
  float* out_mv = out;
  float* out_s  = out + (size_t)BH * N_ * DMV;
  float linv[4];
#pragma unroll
  for (int r = 0; r < 4; ++r)
    linv[r] = __builtin_amdgcn_rcpf(__shfl(l_i, 20 * quad + r));
#pragma unroll
  for (int n9 = 0; n9 < 9; ++n9) {
#pragma unroll
    for (int r = 0; r < 4; ++r) {
      int row = qbase + 16 * w + quad * 4 + r;
      float val = of[n9][r] * linv[r];
      if (n9 < 8) out_mv[(bh_n + row) * DMV + n9 * 16 + l15] = val;
      else        out_s [(bh_n + row) * DS + l15] = val;
    }
  }
}

extern "C" void kernel_launch(void* const* d_in, const int* in_sizes, int n_in,
                              void* d_out, int out_size, void* d_ws, size_t ws_size,
                              hipStream_t stream) {
  (void)in_sizes; (void)n_in; (void)out_size; (void)ws_size;
  const float* q_mv = (const float*)d_in[0];
  const float* k_mv = (const float*)d_in[1];
  const float* v_mv = (const float*)d_in[2];
  const float* q_s  = (const float*)d_in[3];
  const float* k_s  = (const float*)d_in[4];
  const float* v_s  = (const float*)d_in[5];
  float* out = (float*)d_out;

  __bf16* kp = (__bf16*)d_ws;                              // 22,020,096 B
  __bf16* vt = (__bf16*)((char*)d_ws + KP_BYTES);          // 21,233,664 B

  pack_k<<<(BH * N_ * 21) / 256, 256, 0, stream>>>(k_mv, k_s, kp);
  pack_vt<<<BH * NKIT, 256, 0, stream>>>(v_mv, v_s, vt);

  dim3 grid(N_ / BM, BH);
  geo_attn_kernel<<<grid, 512, 0, stream>>>(q_mv, q_s, kp, vt, out);
}